// Round 3
// baseline (413.947 us; speedup 1.0000x reference)
//
#include <hip/hip_runtime.h>

#define T_TOKENS 8192
#define D_MODEL  4096
#define N_EXP    64
#define BT       256          // tokens per gemm block
#define TAU      2e-5f        // gap threshold for f64 repair

#define GLB(p)  ((const __attribute__((address_space(1))) void*)(p))
#define LDSP(p) ((__attribute__((address_space(3))) void*)(p))

// ---------------------------------------------------------------------------
// Kernel 1: f32 partial GEMM. part[ks][t][e] = sum_{k in slice} h[t][k]*w[e][k]
// grid (32, KS), block 256 (4 waves). Tile 256 tokens x 64 experts.
// Staging: global_load_lds width=16 into row-major [t][32] / [e][32] tiles.
// Compute: staggered-k (per-lane k offset) b64 LDS reads -> broadcast,
// conflict-free on h; 8x8 f32 register tile per lane.
// ---------------------------------------------------------------------------
__global__ __launch_bounds__(256) void k_gemm(const float* __restrict__ h,
                                              const float* __restrict__ w,
                                              float* __restrict__ part,
                                              int ks_len) {
    __shared__ float lh[BT][32];     // 32 KB
    __shared__ float lw[N_EXP][32];  //  8 KB
    const int tid  = threadIdx.x;
    const int wv   = tid >> 6;       // wave 0..3
    const int lane = tid & 63;
    const int T0   = blockIdx.x * BT;
    const int k0   = blockIdx.y * ks_len;

    const int tloc = wv * 64 + (lane & 7) * 8;  // 8 consecutive tokens
    const int eloc = (lane >> 3) * 8;           // 8 consecutive experts
    const int ko   = (lane & 15) * 2;           // even k-stagger offset

    float acc[8][8];
#pragma unroll
    for (int i = 0; i < 8; ++i)
#pragma unroll
        for (int j = 0; j < 8; ++j) acc[i][j] = 0.f;

    const int iters = ks_len >> 5;              // 32 k per iter
    for (int it = 0; it < iters; ++it) {
        const int kb = k0 + (it << 5);
        __syncthreads();   // previous compute done before LDS overwrite
        // stage h rows [wv*64 .. wv*64+63]: 8 x 1KB direct-to-LDS
#pragma unroll
        for (int q = 0; q < 8; ++q) {
            const int trow = wv * 64 + q * 8;   // wave-uniform
            const float* g = &h[(size_t)(T0 + trow + (lane >> 3)) * D_MODEL
                                + kb + (lane & 7) * 4];
            __builtin_amdgcn_global_load_lds(GLB(g), LDSP(&lh[trow][0]), 16, 0, 0);
        }
        // stage w rows [wv*16 .. wv*16+15]: 2 x 1KB
#pragma unroll
        for (int q = 0; q < 2; ++q) {
            const int erow = wv * 16 + q * 8;   // wave-uniform
            const float* g = &w[(size_t)(erow + (lane >> 3)) * D_MODEL
                                + kb + (lane & 7) * 4];
            __builtin_amdgcn_global_load_lds(GLB(g), LDSP(&lw[erow][0]), 16, 0, 0);
        }
        __syncthreads();   // compiler drains vmcnt before barrier

#pragma unroll
        for (int u = 0; u < 16; ++u) {
            const int kk = (2 * u + ko) & 31;   // per-lane staggered k (even)
            float2 hv[8], wv2[8];
#pragma unroll
            for (int i = 0; i < 8; ++i)
                hv[i] = *reinterpret_cast<const float2*>(&lh[tloc + i][kk]);
#pragma unroll
            for (int j = 0; j < 8; ++j)
                wv2[j] = *reinterpret_cast<const float2*>(&lw[eloc + j][kk]);
#pragma unroll
            for (int i = 0; i < 8; ++i)
#pragma unroll
                for (int j = 0; j < 8; ++j) {
                    acc[i][j] = fmaf(hv[i].x, wv2[j].x, acc[i][j]);
                    acc[i][j] = fmaf(hv[i].y, wv2[j].y, acc[i][j]);
                }
        }
    }

    float* base = part + ((size_t)blockIdx.y * T_TOKENS + T0) * N_EXP;
#pragma unroll
    for (int i = 0; i < 8; ++i) {
        const int t = tloc + i;
        const float4 o0 = make_float4(acc[i][0], acc[i][1], acc[i][2], acc[i][3]);
        const float4 o1 = make_float4(acc[i][4], acc[i][5], acc[i][6], acc[i][7]);
        *reinterpret_cast<float4*>(&base[(size_t)t * N_EXP + eloc])     = o0;
        *reinterpret_cast<float4*>(&base[(size_t)t * N_EXP + eloc + 4]) = o1;
    }
}

// ---------------------------------------------------------------------------
// Kernel 2: per-token softmax + top-8 + gap-based tie flagging + aux partials.
// block 256 (4 waves), wave handles 4 tokens, lane = expert. f32 throughout.
// Flags token if any adjacent gap among top-9 logits < TAU.
// ---------------------------------------------------------------------------
__global__ __launch_bounds__(256) void k_router(const float* __restrict__ part, int KS,
                                                float* __restrict__ out_idx,
                                                float* __restrict__ out_w,
                                                float* __restrict__ expsum,
                                                int* __restrict__ flag_cnt,
                                                int* __restrict__ flag_list) {
    __shared__ float laux[4][64];
    const int lane = threadIdx.x & 63;
    const int wid  = threadIdx.x >> 6;
    float aux_acc = 0.f;
    const int tbase = blockIdx.x * 16 + wid * 4;

    for (int tt = 0; tt < 4; ++tt) {
        const int t = tbase + tt;
        float lg = 0.f;
        for (int ksi = 0; ksi < KS; ++ksi)
            lg += part[((size_t)ksi * T_TOKENS + t) * N_EXP + lane];

        float m = lg;
#pragma unroll
        for (int off = 32; off; off >>= 1) m = fmaxf(m, __shfl_xor(m, off));
        const float p = __expf(lg - m);
        float s = p;
#pragma unroll
        for (int off = 32; off; off >>= 1) s += __shfl_xor(s, off);
        const float inv_s = 1.f / s;
        aux_acc += p * inv_s;

        // top-9 rounds: select top-8, measure all 9 adjacent gaps
        float pv = lg; int pi = lane;
        float myp = 0.f; int myi = 0; float tsum = 0.f, prev = 0.f;
        bool flg = false;
#pragma unroll
        for (int r = 0; r < 9; ++r) {
            float bv = pv; int bi = pi;
#pragma unroll
            for (int off = 32; off; off >>= 1) {
                const float ov = __shfl_xor(bv, off);
                const int   oi = __shfl_xor(bi, off);
                if (ov > bv || (ov == bv && oi < bi)) { bv = ov; bi = oi; }
            }
            if (r > 0) flg = flg || (prev - bv < TAU);
            prev = bv;
            if (r < 8) {
                const float bp = __expf(bv - m) * inv_s;
                tsum += bp;
                if (lane == r)  { myp = bp; myi = bi; }
                if (lane == bi) pv = -1e30f;
            }
        }
        if (lane < 8) {
            out_idx[(size_t)t * 8 + lane] = (float)myi;
            out_w[(size_t)t * 8 + lane]   = myp / tsum;
        }
        if (lane == 0 && flg) {
            const int pos = atomicAdd(flag_cnt, 1);
            if (pos < T_TOKENS) flag_list[pos] = t;
        }
    }

    laux[wid][lane] = aux_acc;
    __syncthreads();
    if (threadIdx.x < 64)
        expsum[(size_t)blockIdx.x * 64 + threadIdx.x] =
            laux[0][threadIdx.x] + laux[1][threadIdx.x] +
            laux[2][threadIdx.x] + laux[3][threadIdx.x];
}

// ---------------------------------------------------------------------------
// Kernel 3: f64 repair of flagged tokens. 1 wave per token; lane = k-chunk.
// h row held in 16 float4 regs; 64 experts sequential, butterfly f64 reduce.
// ---------------------------------------------------------------------------
__global__ __launch_bounds__(256) void k_repair(const float* __restrict__ h,
                                                const float* __restrict__ w,
                                                const int* __restrict__ flag_cnt,
                                                const int* __restrict__ flag_list,
                                                float* __restrict__ out_idx,
                                                float* __restrict__ out_w) {
    const int lane = threadIdx.x & 63;
    const int wv   = threadIdx.x >> 6;
    const int n = min(*flag_cnt, T_TOKENS);
    for (int i = blockIdx.x * 4 + wv; i < n; i += gridDim.x * 4) {
        const int t = flag_list[i];
        const float* hp = &h[(size_t)t * D_MODEL];
        float4 hr[16];
#pragma unroll
        for (int q = 0; q < 16; ++q)
            hr[q] = *reinterpret_cast<const float4*>(&hp[(q * 64 + lane) * 4]);

        double mylg = 0.0;
        for (int e = 0; e < N_EXP; ++e) {
            const float* wp = &w[(size_t)e * D_MODEL];
            double s = 0.0;
#pragma unroll
            for (int q = 0; q < 16; ++q) {
                const float4 wr = *reinterpret_cast<const float4*>(&wp[(q * 64 + lane) * 4]);
                s = fma((double)hr[q].x, (double)wr.x, s);
                s = fma((double)hr[q].y, (double)wr.y, s);
                s = fma((double)hr[q].z, (double)wr.z, s);
                s = fma((double)hr[q].w, (double)wr.w, s);
            }
#pragma unroll
            for (int off = 32; off; off >>= 1) s += __shfl_xor(s, off);
            if (lane == e) mylg = s;
        }

        double m = mylg;
#pragma unroll
        for (int off = 32; off; off >>= 1) m = fmax(m, __shfl_xor(m, off));
        double pv = mylg; int pi = lane;
        double myp = 0.0; int myi = 0; double tsum = 0.0;
#pragma unroll
        for (int r = 0; r < 8; ++r) {
            double bv = pv; int bi = pi;
#pragma unroll
            for (int off = 32; off; off >>= 1) {
                const double ov = __shfl_xor(bv, off);
                const int    oi = __shfl_xor(bi, off);
                if (ov > bv || (ov == bv && oi < bi)) { bv = ov; bi = oi; }
            }
            const double bp = exp(bv - m);
            tsum += bp;
            if (lane == r)  { myp = bp; myi = bi; }
            if (lane == bi) pv = -1.0e300;
        }
        if (lane < 8) {
            out_idx[(size_t)t * 8 + lane] = (float)myi;
            out_w[(size_t)t * 8 + lane]   = (float)(myp / tsum);
        }
    }
}

// ---------------------------------------------------------------------------
// Kernel 4: aux loss finalize. 1 block, 256 threads (4 slices x 64 experts).
// ---------------------------------------------------------------------------
__global__ __launch_bounds__(256) void k_aux(const float* __restrict__ expsum, int nb,
                                             float* __restrict__ out_aux) {
    __shared__ float l[4][64];
    const int lane  = threadIdx.x & 63;
    const int slice = threadIdx.x >> 6;
    float s = 0.f;
    for (int b = slice; b < nb; b += 4) s += expsum[(size_t)b * 64 + lane];
    l[slice][lane] = s;
    __syncthreads();
    if (threadIdx.x < 64) {
        const float tot = l[0][lane] + l[1][lane] + l[2][lane] + l[3][lane];
        const float avg = tot * (1.f / (float)T_TOKENS);
        float v = avg * avg;
#pragma unroll
        for (int off = 32; off; off >>= 1) v += __shfl_xor(v, off);
        if (lane == 0) out_aux[0] = (float)N_EXP * 0.001f * v;
    }
}

extern "C" void kernel_launch(void* const* d_in, const int* in_sizes, int n_in,
                              void* d_out, int out_size, void* d_ws, size_t ws_size,
                              hipStream_t stream) {
    const float* h = (const float*)d_in[0];   // [8192,4096]
    const float* w = (const float*)d_in[1];   // [64,4096]
    float* out      = (float*)d_out;
    float* out_idx  = out;                    // 65536 (indices as float)
    float* out_w    = out + 65536;            // 65536
    float* out_aux  = out + 131072;           // 1

    const size_t part_elems = (size_t)T_TOKENS * N_EXP;
    const int NB2 = 512;
    int KS = 16;
    while (KS > 1 &&
           ((size_t)KS * part_elems * 4 + (size_t)NB2 * 64 * 4 +
            4 + (size_t)T_TOKENS * 4) > ws_size)
        KS >>= 1;

    float* part     = (float*)d_ws;
    float* expsum   = part + (size_t)KS * part_elems;
    int*   flag_cnt = (int*)(expsum + (size_t)NB2 * 64);
    int*   flag_list= flag_cnt + 1;

    hipMemsetAsync(flag_cnt, 0, sizeof(int), stream);

    dim3 g1(T_TOKENS / BT, KS);
    k_gemm<<<g1, 256, 0, stream>>>(h, w, part, D_MODEL / KS);
    k_router<<<NB2, 256, 0, stream>>>(part, KS, out_idx, out_w, expsum,
                                      flag_cnt, flag_list);
    k_repair<<<256, 256, 0, stream>>>(h, w, flag_cnt, flag_list, out_idx, out_w);
    k_aux<<<1, 256, 0, stream>>>(expsum, NB2, out_aux);
}

// Round 4
// 252.817 us; speedup vs baseline: 1.6373x; 1.6373x over previous
//
#include <hip/hip_runtime.h>

#define T_TOKENS 8192
#define D_MODEL  4096
#define N_EXP    64
#define BT       256          // tokens per gemm block
#define TAU      2e-5f        // gap threshold for f64 repair

#define GLB(p)  ((const __attribute__((address_space(1))) void*)(p))
#define LDSP(p) ((__attribute__((address_space(3))) void*)(p))

// ---------------------------------------------------------------------------
// Kernel 1: f32 partial GEMM. part[ks][t][e] = sum_{k in slice} h[t][k]*w[e][k]
// grid (32, KS), block 256 (4 waves). Tile 256 tokens x 64 experts.
// Staging: global_load_lds width=16 into row-major [t][32] / [e][32] tiles.
// Compute: staggered-k per-lane offset -> broadcast/conflict-light b64 reads;
// 8x8 f32 register tile per lane.
// ---------------------------------------------------------------------------
__global__ __launch_bounds__(256) void k_gemm(const float* __restrict__ h,
                                              const float* __restrict__ w,
                                              float* __restrict__ part,
                                              int ks_len) {
    __shared__ float lh[BT][32];     // 32 KB
    __shared__ float lw[N_EXP][32];  //  8 KB
    const int tid  = threadIdx.x;
    const int wv   = tid >> 6;       // wave 0..3
    const int lane = tid & 63;
    const int T0   = blockIdx.x * BT;
    const int k0   = blockIdx.y * ks_len;

    const int tloc = wv * 64 + (lane & 7) * 8;  // 8 consecutive tokens
    const int eloc = (lane >> 3) * 8;           // 8 consecutive experts
    const int ko   = (lane & 15) * 2;           // even k-stagger offset

    float acc[8][8];
#pragma unroll
    for (int i = 0; i < 8; ++i)
#pragma unroll
        for (int j = 0; j < 8; ++j) acc[i][j] = 0.f;

    const int iters = ks_len >> 5;              // 32 k per iter
    for (int it = 0; it < iters; ++it) {
        const int kb = k0 + (it << 5);
        __syncthreads();   // previous compute done before LDS overwrite
#pragma unroll
        for (int q = 0; q < 8; ++q) {
            const int trow = wv * 64 + q * 8;   // wave-uniform
            const float* g = &h[(size_t)(T0 + trow + (lane >> 3)) * D_MODEL
                                + kb + (lane & 7) * 4];
            __builtin_amdgcn_global_load_lds(GLB(g), LDSP(&lh[trow][0]), 16, 0, 0);
        }
#pragma unroll
        for (int q = 0; q < 2; ++q) {
            const int erow = wv * 16 + q * 8;   // wave-uniform
            const float* g = &w[(size_t)(erow + (lane >> 3)) * D_MODEL
                                + kb + (lane & 7) * 4];
            __builtin_amdgcn_global_load_lds(GLB(g), LDSP(&lw[erow][0]), 16, 0, 0);
        }
        __syncthreads();   // compiler drains vmcnt before barrier

#pragma unroll
        for (int u = 0; u < 16; ++u) {
            const int kk = (2 * u + ko) & 31;   // per-lane staggered k (even)
            float2 hv[8], wv2[8];
#pragma unroll
            for (int i = 0; i < 8; ++i)
                hv[i] = *reinterpret_cast<const float2*>(&lh[tloc + i][kk]);
#pragma unroll
            for (int j = 0; j < 8; ++j)
                wv2[j] = *reinterpret_cast<const float2*>(&lw[eloc + j][kk]);
#pragma unroll
            for (int i = 0; i < 8; ++i)
#pragma unroll
                for (int j = 0; j < 8; ++j) {
                    acc[i][j] = fmaf(hv[i].x, wv2[j].x, acc[i][j]);
                    acc[i][j] = fmaf(hv[i].y, wv2[j].y, acc[i][j]);
                }
        }
    }

    float* base = part + ((size_t)blockIdx.y * T_TOKENS + T0) * N_EXP;
#pragma unroll
    for (int i = 0; i < 8; ++i) {
        const int t = tloc + i;
        const float4 o0 = make_float4(acc[i][0], acc[i][1], acc[i][2], acc[i][3]);
        const float4 o1 = make_float4(acc[i][4], acc[i][5], acc[i][6], acc[i][7]);
        *reinterpret_cast<float4*>(&base[(size_t)t * N_EXP + eloc])     = o0;
        *reinterpret_cast<float4*>(&base[(size_t)t * N_EXP + eloc + 4]) = o1;
    }
}

// ---------------------------------------------------------------------------
// Kernel 2: per-token softmax + top-8 + gap-based tie flagging + aux partials.
// block 256 (4 waves), wave handles 4 tokens, lane = expert. f32 throughout.
// Flags token if any adjacent gap among top-9 logits < TAU.
// ---------------------------------------------------------------------------
__global__ __launch_bounds__(256) void k_router(const float* __restrict__ part, int KS,
                                                float* __restrict__ out_idx,
                                                float* __restrict__ out_w,
                                                float* __restrict__ expsum,
                                                int* __restrict__ flag_cnt,
                                                int* __restrict__ flag_list) {
    __shared__ float laux[4][64];
    const int lane = threadIdx.x & 63;
    const int wid  = threadIdx.x >> 6;
    float aux_acc = 0.f;
    const int tbase = blockIdx.x * 16 + wid * 4;

    for (int tt = 0; tt < 4; ++tt) {
        const int t = tbase + tt;
        float lg = 0.f;
        for (int ksi = 0; ksi < KS; ++ksi)
            lg += part[((size_t)ksi * T_TOKENS + t) * N_EXP + lane];

        float m = lg;
#pragma unroll
        for (int off = 32; off; off >>= 1) m = fmaxf(m, __shfl_xor(m, off));
        const float p = __expf(lg - m);
        float s = p;
#pragma unroll
        for (int off = 32; off; off >>= 1) s += __shfl_xor(s, off);
        const float inv_s = 1.f / s;
        aux_acc += p * inv_s;

        // top-9 rounds: select top-8, measure all 9 adjacent gaps
        float pv = lg; int pi = lane;
        float myp = 0.f; int myi = 0; float tsum = 0.f, prev = 0.f;
        bool flg = false;
#pragma unroll
        for (int r = 0; r < 9; ++r) {
            float bv = pv; int bi = pi;
#pragma unroll
            for (int off = 32; off; off >>= 1) {
                const float ov = __shfl_xor(bv, off);
                const int   oi = __shfl_xor(bi, off);
                if (ov > bv || (ov == bv && oi < bi)) { bv = ov; bi = oi; }
            }
            if (r > 0) flg = flg || (prev - bv < TAU);
            prev = bv;
            if (r < 8) {
                const float bp = __expf(bv - m) * inv_s;
                tsum += bp;
                if (lane == r)  { myp = bp; myi = bi; }
                if (lane == bi) pv = -1e30f;
            }
        }
        if (lane < 8) {
            out_idx[(size_t)t * 8 + lane] = (float)myi;
            out_w[(size_t)t * 8 + lane]   = myp / tsum;
        }
        if (lane == 0 && flg) {
            const int pos = atomicAdd(flag_cnt, 1);
            if (pos < T_TOKENS) flag_list[pos] = t;
        }
    }

    laux[wid][lane] = aux_acc;
    __syncthreads();
    if (threadIdx.x < 64)
        expsum[(size_t)blockIdx.x * 64 + threadIdx.x] =
            laux[0][threadIdx.x] + laux[1][threadIdx.x] +
            laux[2][threadIdx.x] + laux[3][threadIdx.x];
}

// ---------------------------------------------------------------------------
// Kernel 3: f64 repair, ONE BLOCK PER FLAGGED TOKEN (parallel over experts).
// h row staged to LDS (broadcast); thread (e=lane, chunk=wave) computes a
// 1024-elem f64 partial with 4 accumulators; LDS reduce; wave 0 top-8.
// ---------------------------------------------------------------------------
__global__ __launch_bounds__(256) void k_repair(const float* __restrict__ h,
                                                const float* __restrict__ w,
                                                const int* __restrict__ flag_cnt,
                                                const int* __restrict__ flag_list,
                                                float* __restrict__ out_idx,
                                                float* __restrict__ out_w) {
    __shared__ float  sh[D_MODEL];   // 16 KB
    __shared__ double sp[4][64];     //  2 KB
    const int tid  = threadIdx.x;
    const int lane = tid & 63;
    const int c    = tid >> 6;       // k-chunk = wave id
    const int n = min(*flag_cnt, T_TOKENS);

    for (int i = blockIdx.x; i < n; i += gridDim.x) {
        const int t = flag_list[i];
        __syncthreads();   // previous iteration's readers done
#pragma unroll
        for (int q = 0; q < 4; ++q) {
            const int o = (q * 256 + tid) * 4;
            *reinterpret_cast<float4*>(&sh[o]) =
                *reinterpret_cast<const float4*>(&h[(size_t)t * D_MODEL + o]);
        }
        __syncthreads();

        const float* wp = &w[(size_t)lane * D_MODEL + c * 1024];
        const float* hp = &sh[c * 1024];
        double s0 = 0, s1 = 0, s2 = 0, s3 = 0;
        for (int q = 0; q < 256; ++q) {
            const float4 wv = *reinterpret_cast<const float4*>(&wp[q * 4]);
            const float4 hv = *reinterpret_cast<const float4*>(&hp[q * 4]);
            s0 = fma((double)hv.x, (double)wv.x, s0);
            s1 = fma((double)hv.y, (double)wv.y, s1);
            s2 = fma((double)hv.z, (double)wv.z, s2);
            s3 = fma((double)hv.w, (double)wv.w, s3);
        }
        sp[c][lane] = (s0 + s1) + (s2 + s3);
        __syncthreads();

        if (tid < 64) {
            const double mylg = ((sp[0][lane] + sp[1][lane]) +
                                 (sp[2][lane] + sp[3][lane]));
            double m = mylg;
#pragma unroll
            for (int off = 32; off; off >>= 1) m = fmax(m, __shfl_xor(m, off));
            double pv = mylg; int pi = lane;
            double myp = 0.0; int myi = 0; double tsum = 0.0;
#pragma unroll
            for (int r = 0; r < 8; ++r) {
                double bv = pv; int bi = pi;
#pragma unroll
                for (int off = 32; off; off >>= 1) {
                    const double ov = __shfl_xor(bv, off);
                    const int    oi = __shfl_xor(bi, off);
                    if (ov > bv || (ov == bv && oi < bi)) { bv = ov; bi = oi; }
                }
                const double bp = exp(bv - m);
                tsum += bp;
                if (lane == r)  { myp = bp; myi = bi; }
                if (lane == bi) pv = -1.0e300;
            }
            if (lane < 8) {
                out_idx[(size_t)t * 8 + lane] = (float)myi;
                out_w[(size_t)t * 8 + lane]   = (float)(myp / tsum);
            }
        }
    }
}

// ---------------------------------------------------------------------------
// Kernel 4: aux loss finalize. 1 block, 256 threads (4 slices x 64 experts).
// ---------------------------------------------------------------------------
__global__ __launch_bounds__(256) void k_aux(const float* __restrict__ expsum, int nb,
                                             float* __restrict__ out_aux) {
    __shared__ float l[4][64];
    const int lane  = threadIdx.x & 63;
    const int slice = threadIdx.x >> 6;
    float s = 0.f;
    for (int b = slice; b < nb; b += 4) s += expsum[(size_t)b * 64 + lane];
    l[slice][lane] = s;
    __syncthreads();
    if (threadIdx.x < 64) {
        const float tot = l[0][lane] + l[1][lane] + l[2][lane] + l[3][lane];
        const float avg = tot * (1.f / (float)T_TOKENS);
        float v = avg * avg;
#pragma unroll
        for (int off = 32; off; off >>= 1) v += __shfl_xor(v, off);
        if (lane == 0) out_aux[0] = (float)N_EXP * 0.001f * v;
    }
}

extern "C" void kernel_launch(void* const* d_in, const int* in_sizes, int n_in,
                              void* d_out, int out_size, void* d_ws, size_t ws_size,
                              hipStream_t stream) {
    const float* h = (const float*)d_in[0];   // [8192,4096]
    const float* w = (const float*)d_in[1];   // [64,4096]
    float* out      = (float*)d_out;
    float* out_idx  = out;                    // 65536 (indices as float)
    float* out_w    = out + 65536;            // 65536
    float* out_aux  = out + 131072;           // 1

    const size_t part_elems = (size_t)T_TOKENS * N_EXP;
    const int NB2 = 512;
    int KS = 32;                              // 4 blocks/CU (LDS-capped)
    while (KS > 1 &&
           ((size_t)KS * part_elems * 4 + (size_t)NB2 * 64 * 4 +
            4 + (size_t)T_TOKENS * 4) > ws_size)
        KS >>= 1;

    float* part     = (float*)d_ws;
    float* expsum   = part + (size_t)KS * part_elems;
    int*   flag_cnt = (int*)(expsum + (size_t)NB2 * 64);
    int*   flag_list= flag_cnt + 1;

    hipMemsetAsync(flag_cnt, 0, sizeof(int), stream);

    dim3 g1(T_TOKENS / BT, KS);
    k_gemm<<<g1, 256, 0, stream>>>(h, w, part, D_MODEL / KS);
    k_router<<<NB2, 256, 0, stream>>>(part, KS, out_idx, out_w, expsum,
                                      flag_cnt, flag_list);
    k_repair<<<512, 256, 0, stream>>>(h, w, flag_cnt, flag_list, out_idx, out_w);
    k_aux<<<1, 256, 0, stream>>>(expsum, NB2, out_aux);
}

// Round 5
// 191.493 us; speedup vs baseline: 2.1617x; 1.3202x over previous
//
#include <hip/hip_runtime.h>

#define T_TOKENS 8192
#define D_MODEL  4096
#define N_EXP    64
#define BT       256          // tokens per gemm block
#define TAU      4e-6f        // gap threshold for f64 repair (~285 sigma of f32 err)

#define GLB(p)  ((const __attribute__((address_space(1))) void*)(p))
#define LDSP(p) ((__attribute__((address_space(3))) void*)(p))

// ---------------------------------------------------------------------------
// Kernel 1: f32 partial GEMM. part[ks][t][e] = sum_{k in slice} h[t][k]*w[e][k]
// grid (32, KS), block 256 (4 waves). Tile 256 tokens x 64 experts.
// Staging: global_load_lds width=16 into row-major [t][32] / [e][32] tiles.
// Compute: staggered-k per-lane offset -> broadcast/conflict-light b64 reads;
// 8x8 f32 register tile per lane.
// ---------------------------------------------------------------------------
__global__ __launch_bounds__(256) void k_gemm(const float* __restrict__ h,
                                              const float* __restrict__ w,
                                              float* __restrict__ part,
                                              int ks_len) {
    __shared__ float lh[BT][32];     // 32 KB
    __shared__ float lw[N_EXP][32];  //  8 KB
    const int tid  = threadIdx.x;
    const int wv   = tid >> 6;       // wave 0..3
    const int lane = tid & 63;
    const int T0   = blockIdx.x * BT;
    const int k0   = blockIdx.y * ks_len;

    const int tloc = wv * 64 + (lane & 7) * 8;  // 8 consecutive tokens
    const int eloc = (lane >> 3) * 8;           // 8 consecutive experts
    const int ko   = (lane & 15) * 2;           // even k-stagger offset

    float acc[8][8];
#pragma unroll
    for (int i = 0; i < 8; ++i)
#pragma unroll
        for (int j = 0; j < 8; ++j) acc[i][j] = 0.f;

    const int iters = ks_len >> 5;              // 32 k per iter
    for (int it = 0; it < iters; ++it) {
        const int kb = k0 + (it << 5);
        __syncthreads();   // previous compute done before LDS overwrite
#pragma unroll
        for (int q = 0; q < 8; ++q) {
            const int trow = wv * 64 + q * 8;   // wave-uniform
            const float* g = &h[(size_t)(T0 + trow + (lane >> 3)) * D_MODEL
                                + kb + (lane & 7) * 4];
            __builtin_amdgcn_global_load_lds(GLB(g), LDSP(&lh[trow][0]), 16, 0, 0);
        }
#pragma unroll
        for (int q = 0; q < 2; ++q) {
            const int erow = wv * 16 + q * 8;   // wave-uniform
            const float* g = &w[(size_t)(erow + (lane >> 3)) * D_MODEL
                                + kb + (lane & 7) * 4];
            __builtin_amdgcn_global_load_lds(GLB(g), LDSP(&lw[erow][0]), 16, 0, 0);
        }
        __syncthreads();   // compiler drains vmcnt before barrier

#pragma unroll
        for (int u = 0; u < 16; ++u) {
            const int kk = (2 * u + ko) & 31;   // per-lane staggered k (even)
            float2 hv[8], wv2[8];
#pragma unroll
            for (int i = 0; i < 8; ++i)
                hv[i] = *reinterpret_cast<const float2*>(&lh[tloc + i][kk]);
#pragma unroll
            for (int j = 0; j < 8; ++j)
                wv2[j] = *reinterpret_cast<const float2*>(&lw[eloc + j][kk]);
#pragma unroll
            for (int i = 0; i < 8; ++i)
#pragma unroll
                for (int j = 0; j < 8; ++j) {
                    acc[i][j] = fmaf(hv[i].x, wv2[j].x, acc[i][j]);
                    acc[i][j] = fmaf(hv[i].y, wv2[j].y, acc[i][j]);
                }
        }
    }

    float* base = part + ((size_t)blockIdx.y * T_TOKENS + T0) * N_EXP;
#pragma unroll
    for (int i = 0; i < 8; ++i) {
        const int t = tloc + i;
        const float4 o0 = make_float4(acc[i][0], acc[i][1], acc[i][2], acc[i][3]);
        const float4 o1 = make_float4(acc[i][4], acc[i][5], acc[i][6], acc[i][7]);
        *reinterpret_cast<float4*>(&base[(size_t)t * N_EXP + eloc])     = o0;
        *reinterpret_cast<float4*>(&base[(size_t)t * N_EXP + eloc + 4]) = o1;
    }
}

// ---------------------------------------------------------------------------
// Kernel 2: per-token softmax + top-8 + gap-based tie flagging + aux partials.
// block 256 (4 waves), wave handles 4 tokens, lane = expert. f32 throughout.
// Flags token if any adjacent gap among top-9 logits < TAU.
// ---------------------------------------------------------------------------
__global__ __launch_bounds__(256) void k_router(const float* __restrict__ part, int KS,
                                                float* __restrict__ out_idx,
                                                float* __restrict__ out_w,
                                                float* __restrict__ expsum,
                                                int* __restrict__ flag_cnt,
                                                int* __restrict__ flag_list) {
    __shared__ float laux[4][64];
    const int lane = threadIdx.x & 63;
    const int wid  = threadIdx.x >> 6;
    float aux_acc = 0.f;
    const int tbase = blockIdx.x * 16 + wid * 4;

    for (int tt = 0; tt < 4; ++tt) {
        const int t = tbase + tt;
        float lg = 0.f;
        for (int ksi = 0; ksi < KS; ++ksi)
            lg += part[((size_t)ksi * T_TOKENS + t) * N_EXP + lane];

        float m = lg;
#pragma unroll
        for (int off = 32; off; off >>= 1) m = fmaxf(m, __shfl_xor(m, off));
        const float p = __expf(lg - m);
        float s = p;
#pragma unroll
        for (int off = 32; off; off >>= 1) s += __shfl_xor(s, off);
        const float inv_s = 1.f / s;
        aux_acc += p * inv_s;

        // top-9 rounds: select top-8, measure all 9 adjacent gaps
        float pv = lg; int pi = lane;
        float myp = 0.f; int myi = 0; float tsum = 0.f, prev = 0.f;
        bool flg = false;
#pragma unroll
        for (int r = 0; r < 9; ++r) {
            float bv = pv; int bi = pi;
#pragma unroll
            for (int off = 32; off; off >>= 1) {
                const float ov = __shfl_xor(bv, off);
                const int   oi = __shfl_xor(bi, off);
                if (ov > bv || (ov == bv && oi < bi)) { bv = ov; bi = oi; }
            }
            if (r > 0) flg = flg || (prev - bv < TAU);
            prev = bv;
            if (r < 8) {
                const float bp = __expf(bv - m) * inv_s;
                tsum += bp;
                if (lane == r)  { myp = bp; myi = bi; }
                if (lane == bi) pv = -1e30f;
            }
        }
        if (lane < 8) {
            out_idx[(size_t)t * 8 + lane] = (float)myi;
            out_w[(size_t)t * 8 + lane]   = myp / tsum;
        }
        if (lane == 0 && flg) {
            const int pos = atomicAdd(flag_cnt, 1);
            if (pos < T_TOKENS) flag_list[pos] = t;
        }
    }

    laux[wid][lane] = aux_acc;
    __syncthreads();
    if (threadIdx.x < 64)
        expsum[(size_t)blockIdx.x * 64 + threadIdx.x] =
            laux[0][threadIdx.x] + laux[1][threadIdx.x] +
            laux[2][threadIdx.x] + laux[3][threadIdx.x];
}

// ---------------------------------------------------------------------------
// Kernel 3: f64 repair, one block per flagged token. lane = expert, wave = k
// chunk. Inner loop unrolled 8x (16 loads in flight, 8 independent f64 acc)
// to break the R4 latency chain (was: 1 load + 4 dependent FMAs per iter).
// ---------------------------------------------------------------------------
__global__ __launch_bounds__(256) void k_repair(const float* __restrict__ h,
                                                const float* __restrict__ w,
                                                const int* __restrict__ flag_cnt,
                                                const int* __restrict__ flag_list,
                                                float* __restrict__ out_idx,
                                                float* __restrict__ out_w) {
    __shared__ float  sh[D_MODEL];   // 16 KB
    __shared__ double sp[4][64];     //  2 KB
    const int tid  = threadIdx.x;
    const int lane = tid & 63;
    const int c    = tid >> 6;       // k-chunk = wave id
    const int n = min(*flag_cnt, T_TOKENS);

    for (int i = blockIdx.x; i < n; i += gridDim.x) {
        const int t = flag_list[i];
        __syncthreads();   // previous iteration's readers done
#pragma unroll
        for (int q = 0; q < 4; ++q) {
            const int o = (q * 256 + tid) * 4;
            *reinterpret_cast<float4*>(&sh[o]) =
                *reinterpret_cast<const float4*>(&h[(size_t)t * D_MODEL + o]);
        }
        __syncthreads();

        const float* wp = &w[(size_t)lane * D_MODEL + c * 1024];
        const float* hp = &sh[c * 1024];
        double acc[8] = {0, 0, 0, 0, 0, 0, 0, 0};
        for (int q = 0; q < 32; ++q) {          // 32 chunks x 8 float4
            float4 wv8[8], hv8[8];
#pragma unroll
            for (int u = 0; u < 8; ++u) {
                wv8[u] = *reinterpret_cast<const float4*>(&wp[(q * 8 + u) * 4]);
                hv8[u] = *reinterpret_cast<const float4*>(&hp[(q * 8 + u) * 4]);
            }
#pragma unroll
            for (int u = 0; u < 8; ++u) {
                acc[u] = fma((double)hv8[u].x, (double)wv8[u].x, acc[u]);
                acc[u] = fma((double)hv8[u].y, (double)wv8[u].y, acc[u]);
                acc[u] = fma((double)hv8[u].z, (double)wv8[u].z, acc[u]);
                acc[u] = fma((double)hv8[u].w, (double)wv8[u].w, acc[u]);
            }
        }
        sp[c][lane] = (((acc[0] + acc[1]) + (acc[2] + acc[3])) +
                       ((acc[4] + acc[5]) + (acc[6] + acc[7])));
        __syncthreads();

        if (tid < 64) {
            const double mylg = ((sp[0][lane] + sp[1][lane]) +
                                 (sp[2][lane] + sp[3][lane]));
            double m = mylg;
#pragma unroll
            for (int off = 32; off; off >>= 1) m = fmax(m, __shfl_xor(m, off));
            double pv = mylg; int pi = lane;
            double myp = 0.0; int myi = 0; double tsum = 0.0;
#pragma unroll
            for (int r = 0; r < 8; ++r) {
                double bv = pv; int bi = pi;
#pragma unroll
                for (int off = 32; off; off >>= 1) {
                    const double ov = __shfl_xor(bv, off);
                    const int    oi = __shfl_xor(bi, off);
                    if (ov > bv || (ov == bv && oi < bi)) { bv = ov; bi = oi; }
                }
                const double bp = exp(bv - m);
                tsum += bp;
                if (lane == r)  { myp = bp; myi = bi; }
                if (lane == bi) pv = -1.0e300;
            }
            if (lane < 8) {
                out_idx[(size_t)t * 8 + lane] = (float)myi;
                out_w[(size_t)t * 8 + lane]   = (float)(myp / tsum);
            }
        }
    }
}

// ---------------------------------------------------------------------------
// Kernel 4: aux loss finalize. 1 block, 256 threads (4 slices x 64 experts).
// ---------------------------------------------------------------------------
__global__ __launch_bounds__(256) void k_aux(const float* __restrict__ expsum, int nb,
                                             float* __restrict__ out_aux) {
    __shared__ float l[4][64];
    const int lane  = threadIdx.x & 63;
    const int slice = threadIdx.x >> 6;
    float s = 0.f;
    for (int b = slice; b < nb; b += 4) s += expsum[(size_t)b * 64 + lane];
    l[slice][lane] = s;
    __syncthreads();
    if (threadIdx.x < 64) {
        const float tot = l[0][lane] + l[1][lane] + l[2][lane] + l[3][lane];
        const float avg = tot * (1.f / (float)T_TOKENS);
        float v = avg * avg;
#pragma unroll
        for (int off = 32; off; off >>= 1) v += __shfl_xor(v, off);
        if (lane == 0) out_aux[0] = (float)N_EXP * 0.001f * v;
    }
}

extern "C" void kernel_launch(void* const* d_in, const int* in_sizes, int n_in,
                              void* d_out, int out_size, void* d_ws, size_t ws_size,
                              hipStream_t stream) {
    const float* h = (const float*)d_in[0];   // [8192,4096]
    const float* w = (const float*)d_in[1];   // [64,4096]
    float* out      = (float*)d_out;
    float* out_idx  = out;                    // 65536 (indices as float)
    float* out_w    = out + 65536;            // 65536
    float* out_aux  = out + 131072;           // 1

    const size_t part_elems = (size_t)T_TOKENS * N_EXP;
    const int NB2 = 512;
    int KS = 32;                              // 4 blocks/CU (LDS-capped)
    while (KS > 1 &&
           ((size_t)KS * part_elems * 4 + (size_t)NB2 * 64 * 4 +
            4 + (size_t)T_TOKENS * 4) > ws_size)
        KS >>= 1;

    float* part     = (float*)d_ws;
    float* expsum   = part + (size_t)KS * part_elems;
    int*   flag_cnt = (int*)(expsum + (size_t)NB2 * 64);
    int*   flag_list= flag_cnt + 1;

    hipMemsetAsync(flag_cnt, 0, sizeof(int), stream);

    dim3 g1(T_TOKENS / BT, KS);
    k_gemm<<<g1, 256, 0, stream>>>(h, w, part, D_MODEL / KS);
    k_router<<<NB2, 256, 0, stream>>>(part, KS, out_idx, out_w, expsum,
                                      flag_cnt, flag_list);
    k_repair<<<512, 256, 0, stream>>>(h, w, flag_cnt, flag_list, out_idx, out_w);
    k_aux<<<1, 256, 0, stream>>>(expsum, NB2, out_aux);
}